// Round 8
// baseline (156.186 us; speedup 1.0000x reference)
//
#include <hip/hip_runtime.h>
#include <math.h>

// Problem constants (S4Checkpointed): b=2, L=2048, d=768, n=16, r=48
#define BATCH 2
#define LSEQ  2048
#define DIM   768
#define NST   16
#define RDT   48
#define BL    (BATCH*LSEQ)   // 4096
#define NCHUNK 32
#define CLEN   (LSEQ/NCHUNK) // 64
#define CPAD   68            // chunk stride floats: 68%32==4 -> wave's 4 groups on distinct banks
#define NPACK  (CLEN/4)      // 16 float4 packs per chunk
#define LP4    (LSEQ/4)      // 512 t-packs per (b)
#define L2E    1.4426950408889634f

typedef __attribute__((ext_vector_type(8))) short short8;     // 8 bf16 (4 VGPRs)
typedef __attribute__((ext_vector_type(4))) float float4e;    // MFMA acc

__device__ __forceinline__ ushort f2bf(float f) {
    union { float f; unsigned u; } v; v.f = f;
    unsigned u = v.u;
    u += 0x7fffu + ((u >> 16) & 1u);   // round-to-nearest-even
    return (ushort)(u >> 16);
}
__device__ __forceinline__ unsigned pk2bf(float a, float b) {
    return (unsigned)f2bf(a) | ((unsigned)f2bf(b) << 16);
}

// -------- Kernel P: pack x->bf16 + x transpose (float4 both ways) ----------
// grid (32, 13, 2): y<12 -> 64x64 tile of x (b,l,d): writes xbf (bf16, same
// layout, uint2 stores) + xT (fp32, (b,d,l), float4 stores).
// y==12 -> pack 80 live W_xproj rows [0..15|32..47|1584..1631] to bf16.
__global__ __launch_bounds__(256) void pack_kernel(
        const float* __restrict__ x, const float* __restrict__ Wx,
        ushort* __restrict__ xbf, float* __restrict__ xT,
        ushort* __restrict__ Wbf) {
    if (blockIdx.y == 12) {
        const int blk = blockIdx.z * 32 + blockIdx.x;       // 0..63
        for (int idx = blk * 256 + threadIdx.x; idx < 80 * DIM; idx += 64 * 256) {
            const int j = idx / DIM;
            const int k = idx - j * DIM;
            const int row = (j < 16) ? j : ((j < 32) ? (j + 16) : (j + 1552));
            Wbf[idx] = f2bf(Wx[(size_t)row * DIM + k]);
        }
        return;
    }
    __shared__ float tile[64 * 68];
    const int r0 = blockIdx.x * 64;     // l
    const int c0 = blockIdx.y * 64;     // d
    const int b  = blockIdx.z;
    const int tid = threadIdx.x;
    const int c4 = tid & 15;            // float4 column 0..15
    const int rb = tid >> 4;            // 0..15
    #pragma unroll
    for (int rr = 0; rr < 4; ++rr) {
        const int row = rr * 16 + rb;
        const size_t gbase = ((size_t)b * LSEQ + (r0 + row)) * DIM + c0;
        const float4 v = *(const float4*)(x + gbase + c4 * 4);
        *(float4*)&tile[row * 68 + c4 * 4] = v;
        const uint2 bf = make_uint2(pk2bf(v.x, v.y), pk2bf(v.z, v.w));
        *(uint2*)(xbf + gbase + c4 * 4) = bf;
    }
    __syncthreads();
    const int c  = tid & 63;            // column (d offset)
    const int l0 = (tid >> 6) * 16;     // 16 l's per thread
    float* dst = xT + ((size_t)b * DIM + c0 + c) * LSEQ + r0 + l0;
    #pragma unroll
    for (int q = 0; q < 4; ++q) {
        const float4 v = make_float4(tile[(l0 + 4*q + 0) * 68 + c],
                                     tile[(l0 + 4*q + 1) * 68 + c],
                                     tile[(l0 + 4*q + 2) * 68 + c],
                                     tile[(l0 + 4*q + 3) * 68 + c]);
        *(float4*)(dst + 4 * q) = v;
    }
}

// -------- Kernel G: proj GEMM via MFMA -------------------------------------
// M=4096 (bl), N=80 (16 B | 16 C | 48 dt), K=768. One wave per 16-row tile;
// 5 N-tiles x 24 K-iters of mfma_f32_16x16x32_bf16. C/D layout (row=quad*4+reg,
// col=lane&15) lands exactly on pack-transposed Bpk/Cpk + dtpT rows.
__global__ __launch_bounds__(64) void proj_gemm_kernel(
        const ushort* __restrict__ xbf, const ushort* __restrict__ Wbf,
        float* __restrict__ Bpk, float* __restrict__ Cpk,
        float* __restrict__ dtpT) {
    const int m0   = blockIdx.x * 16;   // bl tile base (never straddles b)
    const int lane = threadIdx.x;       // 0..63
    const int col  = lane & 15;
    const int quad = lane >> 4;

    const short* A  = (const short*)xbf + (size_t)(m0 + col) * DIM + quad * 8;
    const short* Bw = (const short*)Wbf;

    float4e acc[5] = {};
    #pragma unroll 6
    for (int kk = 0; kk < 24; ++kk) {
        const short8 a = *(const short8*)(A + kk * 32);
        #pragma unroll
        for (int nt = 0; nt < 5; ++nt) {
            const short8 bf = *(const short8*)(Bw + (size_t)(nt * 16 + col) * DIM + kk * 32 + quad * 8);
            acc[nt] = __builtin_amdgcn_mfma_f32_16x16x32_bf16(a, bf, acc[nt], 0, 0, 0);
        }
    }

    const int b  = m0 >> 11;
    const int t0 = m0 & 2047;
    const size_t pk4 = ((size_t)(b * LP4 + (t0 >> 2) + quad)) * NST + col;
    ((float4*)Bpk)[pk4] = *(float4*)&acc[0];
    ((float4*)Cpk)[pk4] = *(float4*)&acc[1];
    #pragma unroll
    for (int nt = 2; nt < 5; ++nt) {
        const int r = (nt - 2) * 16 + col;
        *(float4*)(dtpT + ((size_t)(b * RDT + r)) * LSEQ + t0 + quad * 4) = *(float4*)&acc[nt];
    }
}

// -------- Kernel T: 64x64 tiled transpose, float4 both ways ----------------
__global__ __launch_bounds__(256) void xpose_kernel(
        const float* __restrict__ in, float* __restrict__ out, int R, int C) {
    __shared__ float tile[64 * 68];
    const int r0 = blockIdx.x * 64;
    const int c0 = blockIdx.y * 64;
    const int b  = blockIdx.z;
    const int tid = threadIdx.x;
    const int c4 = tid & 15;
    const int rb = tid >> 4;
    #pragma unroll
    for (int rr = 0; rr < 4; ++rr) {
        const int row = rr * 16 + rb;
        const float4 v = *(const float4*)(in + ((size_t)b * R + (r0 + row)) * C + c0 + c4 * 4);
        *(float4*)&tile[row * 68 + c4 * 4] = v;
    }
    __syncthreads();
    const int c  = tid & 63;
    const int l0 = (tid >> 6) * 16;
    float* dst = out + ((size_t)b * C + (c0 + c)) * R + r0 + l0;
    #pragma unroll
    for (int q = 0; q < 4; ++q) {
        const float4 v = make_float4(tile[(l0 + 4*q + 0) * 68 + c],
                                     tile[(l0 + 4*q + 1) * 68 + c],
                                     tile[(l0 + 4*q + 2) * 68 + c],
                                     tile[(l0 + 4*q + 3) * 68 + c]);
        *(float4*)(dst + 4 * q) = v;
    }
}

// -------- Kernel C: fused delta + chunked scan (pack-trick, Kogge-Stone) ----
// One block (512 thr) per (b,d); 32 groups x 16 n-lanes; group g owns 64 t.
// VALU diet vs R7: dlx=delta*x precomputed per t (n-invariant), exp2 with
// folded log2e, D-term moved to epilogue.
__global__ __launch_bounds__(512) void scan_kernel(
        const float* __restrict__ xT, const float* __restrict__ z,
        const float* __restrict__ A_log, const float* __restrict__ Dp,
        const float* __restrict__ Bpk, const float* __restrict__ Cpk,
        const float* __restrict__ dtpT, const float* __restrict__ Wdt,
        const float* __restrict__ bdt, float* __restrict__ yT) {
    __shared__ float sdel[NCHUNK * CPAD];   // delta; phase 3 reuses as y buffer
    __shared__ float sdlx[NCHUNK * CPAD];   // delta*x
    __shared__ float sx[NCHUNK * CPAD];     // x (for D-term in epilogue)
    __shared__ float sP[NCHUNK][NST];
    __shared__ float sq[NCHUNK][NST];
    __shared__ float sw[RDT];

    const int tid = threadIdx.x;
    const int ch = blockIdx.x;           // b*768 + d
    const int b = ch / DIM;
    const int d = ch % DIM;
    const size_t row = (size_t)ch * LSEQ;

    // ---- phase 0a: stage x row (padded chunks) + Wdt row to LDS
    if (tid < RDT) sw[tid] = Wdt[(size_t)d * RDT + tid];
    const float4 xv4 = ((const float4*)(xT + row))[tid];
    ((float4*)sx)[(tid >> 4) * (CPAD / 4) + (tid & 15)] = xv4;
    __syncthreads();

    // ---- phase 0b: fused delta -> sdel, delta*x -> sdlx
    {
        const float bb = 2.0f * bdt[d];
        const float* dbase = dtpT + (size_t)b * RDT * LSEQ;
        float4 acc = make_float4(bb, bb, bb, bb);
        #pragma unroll 3
        for (int k4 = 0; k4 < RDT / 4; ++k4) {
            const float4 wv = ((const float4*)sw)[k4];
            #pragma unroll
            for (int j = 0; j < 4; ++j) {
                const int k = k4 * 4 + j;
                const float wk = (j == 0) ? wv.x : (j == 1) ? wv.y : (j == 2) ? wv.z : wv.w;
                const float4 v = ((const float4*)(dbase + (size_t)k * LSEQ))[tid];
                acc.x = fmaf(v.x, wk, acc.x);
                acc.y = fmaf(v.y, wk, acc.y);
                acc.z = fmaf(v.z, wk, acc.z);
                acc.w = fmaf(v.w, wk, acc.w);
            }
        }
        float4 sp;
        sp.x = (acc.x > 20.f) ? acc.x : __logf(1.f + __expf(acc.x));
        sp.y = (acc.y > 20.f) ? acc.y : __logf(1.f + __expf(acc.y));
        sp.z = (acc.z > 20.f) ? acc.z : __logf(1.f + __expf(acc.z));
        sp.w = (acc.w > 20.f) ? acc.w : __logf(1.f + __expf(acc.w));
        const int sidx = (tid >> 4) * (CPAD / 4) + (tid & 15);
        ((float4*)sdel)[sidx] = sp;
        ((float4*)sdlx)[sidx] = make_float4(sp.x * xv4.x, sp.y * xv4.y,
                                            sp.z * xv4.z, sp.w * xv4.w);
    }
    __syncthreads();

    const int g = tid >> 4;          // chunk 0..31
    const int n = tid & 15;          // state index
    const float Aln2 = -__expf(A_log[d * NST + n]) * L2E;  // exp(x)=exp2(x*L2E)
    const float4* Bg = (const float4*)Bpk + ((size_t)(b * LP4 + g * NPACK) * NST + n);
    const float4* Cg = (const float4*)Cpk + ((size_t)(b * LP4 + g * NPACK) * NST + n);
    const float* dchunk  = sdel + g * CPAD;
    const float* uxchunk = sdlx + g * CPAD;

    // ---- phase 1: local scan with pack trick (chain: 1 fma per 4t)
    {
        float h = 0.f, Ptot = 1.f;
        float4 Bn_ = Bg[0];
        #pragma unroll 4
        for (int p = 0; p < NPACK; ++p) {
            const float4 B4 = Bn_;
            if (p < NPACK - 1) Bn_ = Bg[(p + 1) * NST];
            const float4 dl = *(const float4*)(dchunk + 4 * p);
            const float4 ux = *(const float4*)(uxchunk + 4 * p);
            const float u0 = ux.x * B4.x, u1 = ux.y * B4.y;
            const float u2 = ux.z * B4.z, u3 = ux.w * B4.w;
            const float e0  = __builtin_amdgcn_exp2f(Aln2 * dl.x);
            const float dA1 = __builtin_amdgcn_exp2f(Aln2 * dl.y);
            const float dA2 = __builtin_amdgcn_exp2f(Aln2 * dl.z);
            const float dA3 = __builtin_amdgcn_exp2f(Aln2 * dl.w);
            float s = u0;
            s = fmaf(dA1, s, u1); s = fmaf(dA2, s, u2); s = fmaf(dA3, s, u3);
            const float E3 = ((e0 * dA1) * (dA2 * dA3));
            h = fmaf(E3, h, s);          // the only cross-pack chain op
            Ptot *= E3;
        }
        sP[g][n] = Ptot;
        sq[g][n] = h;
    }
    __syncthreads();

    // ---- phase 2: Kogge-Stone inclusive scan of transforms over chunks
    {
        float Pc = sP[g][n], qc = sq[g][n];
        #pragma unroll
        for (int s = 1; s < NCHUNK; s <<= 1) {
            float Pp = 1.f, qp = 0.f;
            if (g >= s) { Pp = sP[g - s][n]; qp = sq[g - s][n]; }
            __syncthreads();
            qc = fmaf(Pc, qp, qc);
            Pc *= Pp;
            sP[g][n] = Pc; sq[g][n] = qc;
            __syncthreads();
        }
    }

    // ---- phase 3: re-scan with carry; h_i independent given pack entry h
    {
        float h = (g == 0) ? 0.f : sq[g - 1][n];
        float* ybuf = sdel;              // reuse: pack p written after pack p read
        float4 Bn_ = Bg[0];
        float4 Cn_ = Cg[0];
        #pragma unroll 4
        for (int p = 0; p < NPACK; ++p) {
            const float4 B4 = Bn_, C4 = Cn_;
            if (p < NPACK - 1) { Bn_ = Bg[(p + 1) * NST]; Cn_ = Cg[(p + 1) * NST]; }
            const float4 dl = *(const float4*)(dchunk + 4 * p);
            const float4 ux = *(const float4*)(uxchunk + 4 * p);
            const float u0 = ux.x * B4.x, u1 = ux.y * B4.y;
            const float u2 = ux.z * B4.z, u3 = ux.w * B4.w;
            const float E0  = __builtin_amdgcn_exp2f(Aln2 * dl.x);
            const float dA1 = __builtin_amdgcn_exp2f(Aln2 * dl.y);
            const float dA2 = __builtin_amdgcn_exp2f(Aln2 * dl.z);
            const float dA3 = __builtin_amdgcn_exp2f(Aln2 * dl.w);
            const float E1 = E0 * dA1, E2 = E1 * dA2, E3 = E2 * dA3;
            const float s0 = u0;
            const float s1 = fmaf(dA1, s0, u1);
            const float s2 = fmaf(dA2, s1, u2);
            const float s3 = fmaf(dA3, s2, u3);
            const float h0 = fmaf(E0, h, s0);
            const float h1 = fmaf(E1, h, s1);
            const float h2 = fmaf(E2, h, s2);
            const float h3 = fmaf(E3, h, s3);
            h = h3;                      // 1-fma cross-pack chain
            float p0 = h0 * C4.x, p1 = h1 * C4.y, p2 = h2 * C4.z, p3 = h3 * C4.w;
            p0 += __shfl_xor(p0, 1); p0 += __shfl_xor(p0, 2);
            p1 += __shfl_xor(p1, 1); p1 += __shfl_xor(p1, 2);
            p2 += __shfl_xor(p2, 1); p2 += __shfl_xor(p2, 2);
            p3 += __shfl_xor(p3, 1); p3 += __shfl_xor(p3, 2);
            float v = (n & 1) ? ((n & 2) ? p3 : p1) : ((n & 2) ? p2 : p0);
            v += __shfl_xor(v, 4);
            v += __shfl_xor(v, 8);
            if (n < 4) ybuf[g * CPAD + 4 * p + n] = v;   // D-term added in epilogue
        }
    }
    __syncthreads();

    // ---- epilogue: y = (ybuf + D*x) * silu(z), write yT (aliases xT)
    {
        const float Dd = Dp[d];
        const float* zrow = z + row;
        float* yrow = yT + row;
        #pragma unroll
        for (int i = tid; i < LSEQ; i += 512) {
            const int idx = (i >> 6) * CPAD + (i & 63);
            const float zv = zrow[i];
            const float sig = 1.0f / (1.0f + __expf(-zv));
            yrow[i] = fmaf(sx[idx], Dd, sdel[idx]) * zv * sig;
        }
    }
}

extern "C" void kernel_launch(void* const* d_in, const int* in_sizes, int n_in,
                              void* d_out, int out_size, void* d_ws, size_t ws_size,
                              hipStream_t stream) {
    const float* x     = (const float*)d_in[0];  // (2,2048,768)
    const float* z     = (const float*)d_in[1];  // (2,768,2048)
    const float* A_log = (const float*)d_in[2];  // (768,16)
    const float* D     = (const float*)d_in[3];  // (768,)
    const float* Wx    = (const float*)d_in[4];  // (1680,768)
    const float* Wdt   = (const float*)d_in[5];  // (768,48)
    const float* bdt   = (const float*)d_in[6];  // (768,)
    float* out = (float*)d_out;

    // ws layout (floats): Bpk | Cpk | dtpT | xT (scan writes yT over it) | xbf | Wbf
    float* ws    = (float*)d_ws;
    float* Bpk   = ws;
    float* Cpk   = Bpk + (size_t)BATCH * LP4 * NST * 4;
    float* dtpT  = Cpk + (size_t)BATCH * LP4 * NST * 4;
    float* xT    = dtpT + (size_t)BATCH * RDT * LSEQ;
    float* yT    = xT;
    ushort* xbf  = (ushort*)(xT + (size_t)BATCH * DIM * LSEQ);
    ushort* Wbf  = xbf + (size_t)BATCH * LSEQ * DIM;

    hipLaunchKernelGGL(pack_kernel, dim3(LSEQ / 64, DIM / 64 + 1, BATCH), dim3(256), 0, stream,
                       x, Wx, xbf, xT, Wbf);
    hipLaunchKernelGGL(proj_gemm_kernel, dim3(BL / 16), dim3(64), 0, stream,
                       xbf, Wbf, Bpk, Cpk, dtpT);
    hipLaunchKernelGGL(scan_kernel, dim3(BATCH * DIM), dim3(512), 0, stream,
                       xT, z, A_log, D, Bpk, Cpk, dtpT, Wdt, bdt, yT);
    hipLaunchKernelGGL(xpose_kernel, dim3(DIM / 64, LSEQ / 64, BATCH), dim3(256), 0, stream,
                       yT, out, DIM, LSEQ);
}